// Round 1
// baseline (233.307 us; speedup 1.0000x reference)
//
#include <hip/hip_runtime.h>
#include <cstdint>
#include <cstddef>

// ---- problem constants ----
#define NBATCH   16384
#define NSEC     9
#define NOC      50        // conv output channels per section
#define NOCP     64        // padded to 4 MFMA n-tiles
#define KPAD     256       // padded K for 8 x 32 MFMA steps
#define KREAL    240
#define XROW     1640      // 41*40 floats per batch
#define XUNITS   208       // 16B-units per LDS row (205 real + 3 zero pad)
#define XSF      1664      // f16 elems per LDS row = XUNITS*8
#define TB       16        // batches per block
#define OUTHALF  7372800   // 16384*50*9
#define THRESH   6.2f

typedef _Float16 half8  __attribute__((ext_vector_type(8)));
typedef float    f32x4  __attribute__((ext_vector_type(4)));

__device__ inline half8 cvt8(float4 a, float4 b) {
    half8 h;
    h[0] = (_Float16)a.x; h[1] = (_Float16)a.y;
    h[2] = (_Float16)a.z; h[3] = (_Float16)a.w;
    h[4] = (_Float16)b.x; h[5] = (_Float16)b.y;
    h[6] = (_Float16)b.z; h[7] = (_Float16)b.w;
    return h;
}

// ---- k0: W fp32 [9][50][240] -> f16 [9][64][256], zero padded ----
__global__ __launch_bounds__(256)
void wconv_kernel(const float* __restrict__ W, _Float16* __restrict__ wks) {
    int idx = blockIdx.x * 256 + threadIdx.x;        // 0 .. 147455
    int k   = idx & 255;
    int ocp = (idx >> 8) & 63;
    int sec = idx >> 14;
    float v = 0.0f;
    if (ocp < NOC && k < KREAL)
        v = W[(size_t)(sec * NOC + ocp) * KREAL + k];
    wks[idx] = (_Float16)v;
}

// ---- fused kernel, h-in-M formulation ----
// M-row m = 4*b_local + h  ->  16 batches = 4 M-tiles of 16 rows.
// wave w: M-tiles {2*(w>>1), +1} (batches 8*(w>>1)..+7), N-tiles {2*(w&1), +1}
// (oc 32*(w&1)..+31).  Each A frag feeds 2 MFMAs, each B frag feeds 2 MFMAs.
// Max-pool over h is a free intra-lane max over the 4 acc registers.
__global__ __launch_bounds__(256, 3)
void fused_kernel(const float* __restrict__ x,
                  const _Float16* __restrict__ wks,
                  float* __restrict__ out) {
    __shared__ __align__(16) _Float16 xs[TB * XSF];   // 53248 B; 3 blocks/CU

    const int tid = threadIdx.x;
    const size_t b0 = (size_t)blockIdx.x * TB;

    // staging geometry: thread t owns row b=t>>4, units u=(t&15)+16j
    // element k of row b lives at unit ((k>>3) ^ (b&7)) (16B runs preserved)
    const int bb  = tid >> 4;
    const int u16 = tid & 15;
    const int ssw = bb & 7;
    const float* xrow = x + (b0 + bb) * XROW;
    _Float16* lrow = xs + bb * XSF;

    // compute-side lane constants
    const int lane  = tid & 63;
    const int w     = tid >> 6;
    const int l15   = lane & 15;
    const int quad  = lane >> 4;
    const int mbase = 8 * (w >> 1);          // batch-local base of this wave
    const int nbase = 32 * (w & 1);          // oc base of this wave

    // A rows for the two m-tiles: row = mbase + 4*mt + (l15>>2), h = l15&3
    const int row0 = mbase + (l15 >> 2);
    const int row1 = row0 + 4;
    const _Float16* arow0 = xs + row0 * XSF;
    const _Float16* arow1 = xs + row1 * XSF;
    const int sw0 = row0 & 7;
    const int sw1 = row1 & 7;
    const int ubase = (l15 & 3) * 5 + quad;  // unit = s*20 + rkk*4 + ubase

    // B: lane covers oc = nbase + nt*16 + l15, elems quad*8..+7, k = kk*32
    const _Float16* wb = wks + (size_t)(nbase + l15) * KPAD + quad * 8;

    // ---- phase-A staging: issue loads for units 0..111 (x rows 0..22) ----
    float4 va[7], vb[7];
    #pragma unroll
    for (int j = 0; j < 7; ++j) {
        int u = u16 + 16 * j;                // <= 111 < 205: no guard needed
        va[j] = *(const float4*)(xrow + u * 8);
        vb[j] = *(const float4*)(xrow + u * 8 + 4);
    }

    // prefetch B chunk 0 (s=0, kk 0..3) while phase-A loads are in flight
    half8 bv[2][2][4];                       // [parity][nt][kk-in-half]
    #pragma unroll
    for (int nt = 0; nt < 2; ++nt)
        #pragma unroll
        for (int kk = 0; kk < 4; ++kk)
            bv[0][nt][kk] = *(const half8*)(wb + (size_t)(nt * 16) * KPAD + kk * 32);

    // convert + write phase-A
    #pragma unroll
    for (int j = 0; j < 7; ++j) {
        int u = u16 + 16 * j;
        *(half8*)(lrow + ((u ^ ssw) << 3)) = cvt8(va[j], vb[j]);
    }
    __syncthreads();                         // rows 0..22 (units 0..111) ready

    float res[NSEC][2][2];                   // [s][mt][nt], pooled scalars
    f32x4 acc[2][2];
    float4 wa[6], wc[6];                     // phase-B staging (rows 22..40)

    // 18 half-section chunks; sections 0..3 == chunks 0..7 need only phase-A
    #pragma unroll
    for (int c = 0; c < 18; ++c) {
        const int s = c >> 1, half = c & 1;

        // prefetch next B chunk into the other buffer
        if (c < 17) {
            const int ns = (c + 1) >> 1, nh = (c + 1) & 1;
            const _Float16* wsec = wb + (size_t)(ns * NOCP) * KPAD + nh * 128;
            #pragma unroll
            for (int nt = 0; nt < 2; ++nt)
                #pragma unroll
                for (int kk = 0; kk < 4; ++kk)
                    bv[(c + 1) & 1][nt][kk] =
                        *(const half8*)(wsec + (size_t)(nt * 16) * KPAD + kk * 32);
        }
        // issue first half of phase-B x loads under early compute
        if (c == 1) {
            #pragma unroll
            for (int j = 0; j < 3; ++j) {
                int u = u16 + 16 * (j + 7);
                if (u < 205) {
                    wa[j] = *(const float4*)(xrow + u * 8);
                    wc[j] = *(const float4*)(xrow + u * 8 + 4);
                } else { wa[j] = float4{0,0,0,0}; wc[j] = float4{0,0,0,0}; }
            }
        }
        // write first half (disjoint units 112+, no barrier needed), issue 2nd
        if (c == 4) {
            #pragma unroll
            for (int j = 0; j < 3; ++j) {
                int u = u16 + 16 * (j + 7);
                *(half8*)(lrow + ((u ^ ssw) << 3)) = cvt8(wa[j], wc[j]);
            }
            #pragma unroll
            for (int j = 3; j < 6; ++j) {
                int u = u16 + 16 * (j + 7);
                if (u < 205) {
                    wa[j] = *(const float4*)(xrow + u * 8);
                    wc[j] = *(const float4*)(xrow + u * 8 + 4);
                } else { wa[j] = float4{0,0,0,0}; wc[j] = float4{0,0,0,0}; }
            }
        }

        if (half == 0) {
            acc[0][0] = f32x4{}; acc[0][1] = f32x4{};
            acc[1][0] = f32x4{}; acc[1][1] = f32x4{};
        }
        #pragma unroll
        for (int kk = 0; kk < 4; ++kk) {
            const int unit = s * 20 + (half * 4 + kk) * 4 + ubase;
            half8 av0 = *(const half8*)(arow0 + ((unit ^ sw0) << 3));
            half8 av1 = *(const half8*)(arow1 + ((unit ^ sw1) << 3));
            acc[0][0] = __builtin_amdgcn_mfma_f32_16x16x32_f16(
                            av0, bv[c & 1][0][kk], acc[0][0], 0, 0, 0);
            acc[0][1] = __builtin_amdgcn_mfma_f32_16x16x32_f16(
                            av0, bv[c & 1][1][kk], acc[0][1], 0, 0, 0);
            acc[1][0] = __builtin_amdgcn_mfma_f32_16x16x32_f16(
                            av1, bv[c & 1][0][kk], acc[1][0], 0, 0, 0);
            acc[1][1] = __builtin_amdgcn_mfma_f32_16x16x32_f16(
                            av1, bv[c & 1][1][kk], acc[1][1], 0, 0, 0);
        }
        if (half == 1) {
            // D row = quad*4+j -> batch = quad, h = j: pool is intra-lane max
            #pragma unroll
            for (int mt = 0; mt < 2; ++mt)
                #pragma unroll
                for (int nt = 0; nt < 2; ++nt)
                    res[s][mt][nt] =
                        fmaxf(fmaxf(acc[mt][nt][0], acc[mt][nt][1]),
                              fmaxf(acc[mt][nt][2], acc[mt][nt][3]));
        }
        // after s=3: finish phase-B staging, then open sections 4..8
        if (c == 7) {
            #pragma unroll
            for (int j = 3; j < 6; ++j) {
                int u = u16 + 16 * (j + 7);
                *(half8*)(lrow + ((u ^ ssw) << 3)) = cvt8(wa[j], wc[j]);
            }
            __syncthreads();                 // units 112..207 now ready
        }
    }

    // ---- reuse xs as fp32 transpose buffer t[16][450] ----
    __syncthreads();
    float* tb = (float*)xs;
    #pragma unroll
    for (int mt = 0; mt < 2; ++mt) {
        const int bl = mbase + 4 * mt + quad;
        #pragma unroll
        for (int nt = 0; nt < 2; ++nt) {
            const int oc = nbase + nt * 16 + l15;
            if (oc < NOC) {
                #pragma unroll
                for (int s = 0; s < NSEC; ++s)
                    tb[bl * 450 + oc * 9 + s] = res[s][mt][nt];
            }
        }
    }
    __syncthreads();

    // coalesced float4 final write: pots then spikes
    const size_t ob = b0 * 450;
    const float4* t4 = (const float4*)tb;
    float4* o4  = (float4*)(out + ob);
    float4* o4s = (float4*)(out + OUTHALF + ob);
    for (int i = tid; i < TB * 450 / 4; i += 256) {
        float4 v = t4[i];
        o4[i] = v;
        float4 sp;
        sp.x = (v.x > THRESH) ? 1.0f : 0.0f;
        sp.y = (v.y > THRESH) ? 1.0f : 0.0f;
        sp.z = (v.z > THRESH) ? 1.0f : 0.0f;
        sp.w = (v.w > THRESH) ? 1.0f : 0.0f;
        o4s[i] = sp;
    }
}

// ---- fallback (only if ws too small): direct fp32, correct but slow ----
__global__ __launch_bounds__(256)
void naive_kernel(const float* __restrict__ x, const float* __restrict__ W,
                  float* __restrict__ out) {
    size_t idx = (size_t)blockIdx.x * 256 + threadIdx.x;
    if (idx >= OUTHALF) return;
    int s  = (int)(idx % NSEC);
    int oc = (int)((idx / NSEC) % NOC);
    int b  = (int)(idx / (NSEC * NOC));
    const float* xb = x + (size_t)b * XROW + s * 160;
    const float* wv = W + (size_t)(s * NOC + oc) * KREAL;
    float best = -1e30f;
    for (int h0 = 0; h0 < 4; ++h0) {
        float acc = 0.0f;
        for (int k = 0; k < KREAL; ++k)
            acc += xb[h0 * 40 + k] * wv[k];
        best = fmaxf(best, acc);
    }
    out[idx] = best;
    out[OUTHALF + idx] = (best > THRESH) ? 1.0f : 0.0f;
}

extern "C" void kernel_launch(void* const* d_in, const int* in_sizes, int n_in,
                              void* d_out, int out_size, void* d_ws, size_t ws_size,
                              hipStream_t stream) {
    const float* x = (const float*)d_in[0];   // [16384,1,41,40]
    const float* W = (const float*)d_in[1];   // [9,50,1,6,40]
    float* out = (float*)d_out;               // pots(7372800) ++ spks(7372800)

    const size_t w_bytes = (size_t)NSEC * NOCP * KPAD * sizeof(_Float16); // 294912

    if (ws_size < w_bytes) {
        naive_kernel<<<(OUTHALF + 255) / 256, 256, 0, stream>>>(x, W, out);
        return;
    }

    _Float16* wks = (_Float16*)d_ws;

    wconv_kernel<<<(NSEC * NOCP * KPAD) / 256, 256, 0, stream>>>(W, wks);
    fused_kernel<<<NBATCH / TB, 256, 0, stream>>>(x, wks, out);
}

// Round 3
// 231.171 us; speedup vs baseline: 1.0092x; 1.0092x over previous
//
#include <hip/hip_runtime.h>
#include <cstdint>
#include <cstddef>

// ---- problem constants ----
#define NBATCH   16384
#define NSEC     9
#define NOC      50        // conv output channels per section
#define NOCP     64        // padded to 4 MFMA n-tiles
#define KPAD     256       // padded K for 8 x 32 MFMA steps
#define KREAL    240
#define XROW     1640      // 41*40 floats per batch
#define XSF      1664      // f16 elems per LDS row = 208 units * 8
#define TB       16        // batches per block
#define OUTHALF  7372800   // 16384*50*9
#define THRESH   6.2f

typedef _Float16 half8  __attribute__((ext_vector_type(8)));
typedef float    f32x4  __attribute__((ext_vector_type(4)));

__device__ inline half8 cvt8(float4 a, float4 b) {
    half8 h;
    h[0] = (_Float16)a.x; h[1] = (_Float16)a.y;
    h[2] = (_Float16)a.z; h[3] = (_Float16)a.w;
    h[4] = (_Float16)b.x; h[5] = (_Float16)b.y;
    h[6] = (_Float16)b.z; h[7] = (_Float16)b.w;
    return h;
}

__device__ inline void stg_load(const float* __restrict__ xrow, int u,
                                float4& a, float4& b) {
    if (u < 205) {           // 205*8 == 1640 exactly
        a = *(const float4*)(xrow + u * 8);
        b = *(const float4*)(xrow + u * 8 + 4);
    } else {
        a = float4{0, 0, 0, 0};
        b = float4{0, 0, 0, 0};
    }
}

__device__ inline void stg_write(_Float16* lrow, int u, int ssw,
                                 float4 a, float4 b) {
    *(half8*)(lrow + ((u ^ ssw) << 3)) = cvt8(a, b);
}

// ---- k0: W fp32 [9][50][240] -> f16 [9][64][256], zero padded ----
__global__ __launch_bounds__(256)
void wconv_kernel(const float* __restrict__ W, _Float16* __restrict__ wks) {
    int idx = blockIdx.x * 256 + threadIdx.x;        // 0 .. 147455
    int k   = idx & 255;
    int ocp = (idx >> 8) & 63;
    int sec = idx >> 14;
    float v = 0.0f;
    if (ocp < NOC && k < KREAL)
        v = W[(size_t)(sec * NOC + ocp) * KREAL + k];
    wks[idx] = (_Float16)v;
}

// ---- fused kernel, h-in-M formulation, straight-line codegen ----
// M-row m = 4*b_local + h.  wave w: batches 8*(w>>1)..+7 (2 m-tiles),
// oc 32*(w&1)..+31 (2 n-tiles).  Each A frag feeds 2 MFMAs, each B frag 2.
// Pool over h = intra-lane max over the 4 acc regs (D row = quad*4+j).
__global__ __launch_bounds__(256, 3)
void fused_kernel(const float* __restrict__ x,
                  const _Float16* __restrict__ wks,
                  float* __restrict__ out) {
    __shared__ __align__(16) _Float16 xs[TB * XSF];   // 53248 B; 3 blocks/CU

    const int tid = threadIdx.x;
    const size_t b0 = (size_t)blockIdx.x * TB;

    // staging geometry: thread t owns row b=t>>4, units u=(t&15)+16j
    // element k of row b lives at unit ((k>>3) ^ (b&7)) (16B runs preserved)
    const int bb  = tid >> 4;
    const int u16 = tid & 15;
    const int ssw = bb & 7;
    const float* xrow = x + (b0 + bb) * XROW;
    _Float16* lrow = xs + bb * XSF;

    // compute-side lane constants
    const int lane  = tid & 63;
    const int w     = tid >> 6;
    const int l15   = lane & 15;
    const int quad  = lane >> 4;
    const int mbase = 8 * (w >> 1);          // batch-local base of this wave
    const int nbase = 32 * (w & 1);          // oc base of this wave

    // A rows for the two m-tiles: batch = mbase + 4*mt + (l15>>2), h = l15&3
    const int row0 = mbase + (l15 >> 2);
    const int row1 = row0 + 4;
    const _Float16* arow0 = xs + row0 * XSF;
    const _Float16* arow1 = xs + row1 * XSF;
    const int sw0 = row0 & 7;
    const int sw1 = row1 & 7;
    const int ubase = (l15 & 3) * 5 + quad;  // unit = s*20 + (h4+kk)*4 + ubase

    // B: lane covers oc = nbase + nt*16 + l15, elems quad*8..+7, k chunk kk*32
    const _Float16* wb = wks + (size_t)(nbase + l15) * KPAD + quad * 8;

    half8 bv0[2][4], bv1[2][4];              // two half-section B buffers
    f32x4 acc00, acc01, acc10, acc11;
    float res[NSEC][2][2];

#define BPREF(ss, hh, B) { \
    const _Float16* wsec_ = wb + (size_t)((ss) * NOCP) * KPAD + (hh) * 128; \
    B[0][0] = *(const half8*)(wsec_);                \
    B[0][1] = *(const half8*)(wsec_ + 32);           \
    B[0][2] = *(const half8*)(wsec_ + 64);           \
    B[0][3] = *(const half8*)(wsec_ + 96);           \
    B[1][0] = *(const half8*)(wsec_ + 16 * KPAD);        \
    B[1][1] = *(const half8*)(wsec_ + 16 * KPAD + 32);   \
    B[1][2] = *(const half8*)(wsec_ + 16 * KPAD + 64);   \
    B[1][3] = *(const half8*)(wsec_ + 16 * KPAD + 96);   \
}

#define CHALF(ss, hh, B) { \
    _Pragma("unroll") \
    for (int kk = 0; kk < 4; ++kk) { \
        const int unit_ = (ss) * 20 + ((hh) * 4 + kk) * 4 + ubase; \
        half8 av0_ = *(const half8*)(arow0 + ((unit_ ^ sw0) << 3)); \
        half8 av1_ = *(const half8*)(arow1 + ((unit_ ^ sw1) << 3)); \
        acc00 = __builtin_amdgcn_mfma_f32_16x16x32_f16(av0_, B[0][kk], acc00, 0, 0, 0); \
        acc01 = __builtin_amdgcn_mfma_f32_16x16x32_f16(av0_, B[1][kk], acc01, 0, 0, 0); \
        acc10 = __builtin_amdgcn_mfma_f32_16x16x32_f16(av1_, B[0][kk], acc10, 0, 0, 0); \
        acc11 = __builtin_amdgcn_mfma_f32_16x16x32_f16(av1_, B[1][kk], acc11, 0, 0, 0); \
    } \
}

#define SECTION(ss) { \
    BPREF(ss, 1, bv1); \
    acc00 = f32x4{}; acc01 = f32x4{}; acc10 = f32x4{}; acc11 = f32x4{}; \
    CHALF(ss, 0, bv0); \
    if ((ss) < 8) BPREF((ss) + 1, 0, bv0); \
    CHALF(ss, 1, bv1); \
    res[ss][0][0] = fmaxf(fmaxf(acc00[0], acc00[1]), fmaxf(acc00[2], acc00[3])); \
    res[ss][0][1] = fmaxf(fmaxf(acc01[0], acc01[1]), fmaxf(acc01[2], acc01[3])); \
    res[ss][1][0] = fmaxf(fmaxf(acc10[0], acc10[1]), fmaxf(acc10[2], acc10[3])); \
    res[ss][1][1] = fmaxf(fmaxf(acc11[0], acc11[1]), fmaxf(acc11[2], acc11[3])); \
}

    // ---- phase-A staging: units 0..111 (x rows 0..22, covers s0..s3) ----
    {
        float4 va[7], vb[7];
        #pragma unroll
        for (int j = 0; j < 7; ++j) {
            const int u = u16 + 16 * j;      // <= 111 < 205: no guard
            va[j] = *(const float4*)(xrow + u * 8);
            vb[j] = *(const float4*)(xrow + u * 8 + 4);
        }
        BPREF(0, 0, bv0);                    // B s0/h0 under staging latency
        #pragma unroll
        for (int j = 0; j < 7; ++j)
            stg_write(lrow, u16 + 16 * j, ssw, va[j], vb[j]);
    }
    __syncthreads();                         // units 0..111 ready

    // phase-B staging (units 112..207) in 3 parts, hidden under s0..s2
    float4 pa0, pb0, pa1, pb1;
    stg_load(xrow, u16 + 112, pa0, pb0);
    stg_load(xrow, u16 + 128, pa1, pb1);

    SECTION(0);
    stg_write(lrow, u16 + 112, ssw, pa0, pb0);   // disjoint from s0..3 reads
    stg_write(lrow, u16 + 128, ssw, pa1, pb1);
    stg_load(xrow, u16 + 144, pa0, pb0);
    stg_load(xrow, u16 + 160, pa1, pb1);
    SECTION(1);
    stg_write(lrow, u16 + 144, ssw, pa0, pb0);
    stg_write(lrow, u16 + 160, ssw, pa1, pb1);
    stg_load(xrow, u16 + 176, pa0, pb0);
    stg_load(xrow, u16 + 192, pa1, pb1);
    SECTION(2);
    stg_write(lrow, u16 + 176, ssw, pa0, pb0);
    stg_write(lrow, u16 + 192, ssw, pa1, pb1);
    SECTION(3);
    __syncthreads();                         // units 112..207 now ready
    SECTION(4);
    SECTION(5);
    SECTION(6);
    SECTION(7);
    SECTION(8);

    // ---- reuse xs as fp32 transpose buffer t[16][450] ----
    __syncthreads();
    float* tb = (float*)xs;
    #pragma unroll
    for (int mt = 0; mt < 2; ++mt) {
        const int bl = mbase + 4 * mt + quad;
        #pragma unroll
        for (int nt = 0; nt < 2; ++nt) {
            const int oc = nbase + nt * 16 + l15;
            if (oc < NOC) {
                #pragma unroll
                for (int s = 0; s < NSEC; ++s)
                    tb[bl * 450 + oc * 9 + s] = res[s][mt][nt];
            }
        }
    }
    __syncthreads();

    // coalesced float4 final write: pots then spikes
    const size_t ob = b0 * 450;
    const float4* t4 = (const float4*)tb;
    float4* o4  = (float4*)(out + ob);
    float4* o4s = (float4*)(out + OUTHALF + ob);
    for (int i = tid; i < TB * 450 / 4; i += 256) {
        float4 v = t4[i];
        o4[i] = v;
        float4 sp;
        sp.x = (v.x > THRESH) ? 1.0f : 0.0f;
        sp.y = (v.y > THRESH) ? 1.0f : 0.0f;
        sp.z = (v.z > THRESH) ? 1.0f : 0.0f;
        sp.w = (v.w > THRESH) ? 1.0f : 0.0f;
        o4s[i] = sp;
    }
}

// ---- fallback (only if ws too small): direct fp32, correct but slow ----
__global__ __launch_bounds__(256)
void naive_kernel(const float* __restrict__ x, const float* __restrict__ W,
                  float* __restrict__ out) {
    size_t idx = (size_t)blockIdx.x * 256 + threadIdx.x;
    if (idx >= OUTHALF) return;
    int s  = (int)(idx % NSEC);
    int oc = (int)((idx / NSEC) % NOC);
    int b  = (int)(idx / (NSEC * NOC));
    const float* xb = x + (size_t)b * XROW + s * 160;
    const float* wv = W + (size_t)(s * NOC + oc) * KREAL;
    float best = -1e30f;
    for (int h0 = 0; h0 < 4; ++h0) {
        float acc = 0.0f;
        for (int k = 0; k < KREAL; ++k)
            acc += xb[h0 * 40 + k] * wv[k];
        best = fmaxf(best, acc);
    }
    out[idx] = best;
    out[OUTHALF + idx] = (best > THRESH) ? 1.0f : 0.0f;
}

extern "C" void kernel_launch(void* const* d_in, const int* in_sizes, int n_in,
                              void* d_out, int out_size, void* d_ws, size_t ws_size,
                              hipStream_t stream) {
    const float* x = (const float*)d_in[0];   // [16384,1,41,40]
    const float* W = (const float*)d_in[1];   // [9,50,1,6,40]
    float* out = (float*)d_out;               // pots(7372800) ++ spks(7372800)

    const size_t w_bytes = (size_t)NSEC * NOCP * KPAD * sizeof(_Float16); // 294912

    if (ws_size < w_bytes) {
        naive_kernel<<<(OUTHALF + 255) / 256, 256, 0, stream>>>(x, W, out);
        return;
    }

    _Float16* wks = (_Float16*)d_ws;

    wconv_kernel<<<(NSEC * NOCP * KPAD) / 256, 256, 0, stream>>>(W, wks);
    fused_kernel<<<NBATCH / TB, 256, 0, stream>>>(x, wks, out);
}